// Round 13
// baseline (158.171 us; speedup 1.0000x reference)
//
#include <hip/hip_runtime.h>

// Problem constants
#define NNODES 64
#define HID 32
#define NFACT 3
#define NE 1024
#define NROWS (NE + NFACT)   // 1027
#define TPB 256
#define STR 36               // row stride (floats) for xpp/qp
#define MAXQT 320            // quad-tile capacity: sum ceil(deg/4) <= (1024+64*3)/4 = 304
#define EPT (NE / TPB)       // 4 edges cached per thread

typedef short bf16x8 __attribute__((ext_vector_type(8)));
typedef float f32x4  __attribute__((ext_vector_type(4)));
typedef float f32x16 __attribute__((ext_vector_type(16)));

// round-to-nearest-even two fp32 -> packed bf16x2 (lo | hi<<16)
__device__ __forceinline__ unsigned pack_bf2(float lo, float hi) {
    unsigned ul = __builtin_bit_cast(unsigned, lo);
    unsigned uh = __builtin_bit_cast(unsigned, hi);
    ul += 0x7fffu + ((ul >> 16) & 1u);
    uh += 0x7fffu + ((uh >> 16) & 1u);
    return (ul >> 16) | (uh & 0xffff0000u);
}
__device__ __forceinline__ short f2bf(float f) {
    unsigned u = __builtin_bit_cast(unsigned, f);
    u += 0x7fffu + ((u >> 16) & 1u);
    return (short)(u >> 16);
}
__device__ __forceinline__ float4 fma4(float a, float4 w, float4 c) {
    c.x = fmaf(a, w.x, c.x); c.y = fmaf(a, w.y, c.y);
    c.z = fmaf(a, w.z, c.z); c.w = fmaf(a, w.w, c.w);
    return c;
}

// Single fused kernel. CSR built per block in LDS with 4-EDGE-granular tiles
// (12.5% pad vs 47% at 16-edge granularity). Stage B reduces per 4-row group
// straight out of the 32x32 MFMA C-layout (regs {0-3}{4-7}{8-11}{12-15} =
// rows {0-3}{8-11}{16-19}{24-27}+4*half) -> 4 contiguous atomics, no shfl.
//   pep packed: low12 = edge id (0xFFF = pad), bits12-17 = dst, bits18-23 = src
//   pad entries keep node 0: pad lanes force af=0, padded groups add 0.0 to node 0.
__global__ __launch_bounds__(TPB, 4) void critic_fused(
    const float* __restrict__ x,
    const float* __restrict__ edge_attr,
    const float* __restrict__ action,
    const int*   __restrict__ es,
    const int*   __restrict__ ed,
    const float* __restrict__ W1,
    const float* __restrict__ b1,
    const float* __restrict__ W2,
    const float* __restrict__ b2,
    const float* __restrict__ Wl,
    const float* __restrict__ bl,
    const float* __restrict__ Wv,
    const float* __restrict__ bv,
    float* __restrict__ out)
{
    const int b    = blockIdx.x;
    const int tid  = threadIdx.x;
    const int lane = tid & 63;
    const int wv   = tid >> 6;
    const int quad = lane >> 4;
    const int m16  = lane & 15;
    const int kh   = quad * 8;

    __shared__ float4 xs4[NNODES];
    __shared__ float  xpp[NNODES * STR];
    __shared__ float  qp0[NNODES * STR];      // Q1 then P1
    __shared__ float  qp1[NNODES * STR];      // Q2 then P2
    __shared__ float  W1s[10 * HID];
    __shared__ float  b1s[HID];
    __shared__ float  wred[TPB / 64];
    // CSR tables (built per block, quad-tile granular)
    __shared__ int    sdeg[NNODES], soff[NNODES], scnt[NNODES];
    __shared__ int    tns4[MAXQT];            // quad-tile -> node
    __shared__ int    pep[MAXQT * 4];         // edge slots
    __shared__ int    snt4;

    // ---- Stage A: stage x + W1, zero xpp, init CSR tables ----
    if (tid < NNODES) { xs4[tid] = ((const float4*)x)[b * NNODES + tid]; sdeg[tid] = 0; scnt[tid] = 0; }
    if (tid < 80) ((float4*)W1s)[tid] = ((const float4*)W1)[tid];
    if (tid < HID) b1s[tid] = b1[tid];
#pragma unroll
    for (int i = 0; i < MAXQT / TPB + 1; i++) {
        const int j = tid + i * TPB;
        if (j < MAXQT) tns4[j] = 0;
    }
#pragma unroll
    for (int i = 0; i < MAXQT * 4 / TPB; i++) pep[tid + i * TPB] = 0xFFF;   // pad, node 0
#pragma unroll 1
    for (int i = tid; i < NNODES * STR; i += TPB) xpp[i] = 0.0f;

    // cache this thread's 4 edges in registers (coalesced global reads)
    int ces[EPT], ced[EPT];
#pragma unroll
    for (int i = 0; i < EPT; i++) {
        ces[i] = es[tid + i * TPB];
        ced[i] = ed[tid + i * TPB];
    }
    __syncthreads();

    // ---- CSR count + Stage Q (independent; co-scheduled to hide latency) ----
#pragma unroll
    for (int i = 0; i < EPT; i++) atomicAdd(&sdeg[ces[i]], 1);
    {
        const int n  = lane;
        const int k0 = wv * 8;
        const float4 xv = xs4[n];
        const float4* b1v = (const float4*)&b1s[k0];
        float4 q1a = b1v[0], q1b = b1v[1];
        float4 q2a = make_float4(0.f, 0.f, 0.f, 0.f), q2b = q2a;
#pragma unroll 1
        for (int i = 0; i < 4; i++) {
            const float xi = (i == 0) ? xv.x : (i == 1) ? xv.y : (i == 2) ? xv.z : xv.w;
            const float4* wa = (const float4*)&W1s[i * HID + k0];
            const float4* wb = (const float4*)&W1s[(4 + i) * HID + k0];
            q1a = fma4(xi, wa[0], q1a); q1b = fma4(xi, wa[1], q1b);
            q2a = fma4(xi, wb[0], q2a); q2b = fma4(xi, wb[1], q2b);
        }
        float4* q1w = (float4*)&qp0[n * STR + k0];
        float4* q2w = (float4*)&qp1[n * STR + k0];
        q1w[0] = q1a; q1w[1] = q1b;
        q2w[0] = q2a; q2w[1] = q2b;
    }
    __syncthreads();

    // ---- CSR scan (wave 0) + tile-node fill ----
    if (tid < NNODES) {
        const int cnt = (sdeg[tid] + 3) >> 2;        // quad-tiles for this node
        int scan = cnt;
#pragma unroll
        for (int o = 1; o < 64; o <<= 1) {
            const int v = __shfl_up(scan, o);
            if (tid >= o) scan += v;
        }
        const int base = scan - cnt;
        soff[tid] = base;
        if (tid == NNODES - 1) snt4 = scan;          // total quad-tiles (~288, <=304)
#pragma unroll 1
        for (int j = 0; j < cnt; j++) tns4[base + j] = tid;
    }
    __syncthreads();

    // ---- CSR scatter (cached edges) ----
#pragma unroll
    for (int i = 0; i < EPT; i++) {
        const int n = ces[i];
        const int idx = atomicAdd(&scnt[n], 1);
        pep[soff[n] * 4 + idx] = (tid + i * TPB) | (ced[i] << 12) | (n << 18);
    }
    __syncthreads();

    // ---- Stage B: MFMA edge messages, 32 edge-slots (8 quad-groups) per iteration ----
    {
        const float2* ea2 = (const float2*)edge_attr + (size_t)b * NE;
        const int NW  = TPB / 64;
        const int klo = (lane >> 5) * 8;      // this lane's K-slice base (0 or 8)
        const int n32 = lane & 31;
        const int hf  = lane >> 5;            // half index: group parity

        const float4* w8l = (const float4*)&W1s[8 * HID + klo];
        const float4* w8h = (const float4*)&W1s[8 * HID + 16 + klo];
        const float4* w9l = (const float4*)&W1s[9 * HID + klo];
        const float4* w9h = (const float4*)&W1s[9 * HID + 16 + klo];
        const float4 w8a = w8l[0], w8b = w8l[1], w8c = w8h[0], w8d = w8h[1];
        const float4 w9a = w9l[0], w9b = w9l[1], w9c = w9h[0], w9d = w9h[1];

        bf16x8 bfA, bfB;   // W2 B-frags: B[k][n32], K-halves 0..15 / 16..31
#pragma unroll
        for (int j = 0; j < 8; j++) {
            bfA[j] = f2bf(W2[(klo + j) * HID + n32]);
            bfB[j] = f2bf(W2[(16 + klo + j) * HID + n32]);
        }

        const int np = (snt4 + 7) >> 3;       // ~36 iterations (ideal 32)

#pragma unroll 1
        for (int p = wv; p < np; p += NW) {
            const int raw = pep[p * 32 + n32];        // edge slot = window row n32
            const int e    = raw & 0xFFF;
            const bool pad = (e == 0xFFF);
            const int d0   = (raw >> 12) & 63;
            const int nd   = (raw >> 18) & 63;        // src node of MY edge (gather)
            const float2 ea = ea2[pad ? 0 : e];
            // group nodes for this lane's 4 row-groups
            const int t0 = tns4[p * 8 + hf];
            const int t1 = tns4[p * 8 + 2 + hf];
            const int t2 = tns4[p * 8 + 4 + hf];
            const int t3 = tns4[p * 8 + 6 + hf];

            const float4* A1 = (const float4*)&qp0[nd * STR + klo];
            const float4* A2 = (const float4*)&qp0[nd * STR + 16 + klo];
            const float4* G1 = (const float4*)&qp1[d0 * STR + klo];
            const float4* G2 = (const float4*)&qp1[d0 * STR + 16 + klo];
            const float4 a0 = A1[0], a1 = A1[1], a2 = A2[0], a3 = A2[1];
            const float4 g0 = G1[0], g1 = G1[1], g2 = G2[0], g3 = G2[1];

            const float hx0 = fmaxf(a0.x + g0.x + ea.x * w8a.x + ea.y * w9a.x, 0.f);
            const float hx1 = fmaxf(a0.y + g0.y + ea.x * w8a.y + ea.y * w9a.y, 0.f);
            const float hx2 = fmaxf(a0.z + g0.z + ea.x * w8a.z + ea.y * w9a.z, 0.f);
            const float hx3 = fmaxf(a0.w + g0.w + ea.x * w8a.w + ea.y * w9a.w, 0.f);
            const float hx4 = fmaxf(a1.x + g1.x + ea.x * w8b.x + ea.y * w9b.x, 0.f);
            const float hx5 = fmaxf(a1.y + g1.y + ea.x * w8b.y + ea.y * w9b.y, 0.f);
            const float hx6 = fmaxf(a1.z + g1.z + ea.x * w8b.z + ea.y * w9b.z, 0.f);
            const float hx7 = fmaxf(a1.w + g1.w + ea.x * w8b.w + ea.y * w9b.w, 0.f);
            const float hy0 = fmaxf(a2.x + g2.x + ea.x * w8c.x + ea.y * w9c.x, 0.f);
            const float hy1 = fmaxf(a2.y + g2.y + ea.x * w8c.y + ea.y * w9c.y, 0.f);
            const float hy2 = fmaxf(a2.z + g2.z + ea.x * w8c.z + ea.y * w9c.z, 0.f);
            const float hy3 = fmaxf(a2.w + g2.w + ea.x * w8c.w + ea.y * w9c.w, 0.f);
            const float hy4 = fmaxf(a3.x + g3.x + ea.x * w8d.x + ea.y * w9d.x, 0.f);
            const float hy5 = fmaxf(a3.y + g3.y + ea.x * w8d.y + ea.y * w9d.y, 0.f);
            const float hy6 = fmaxf(a3.z + g3.z + ea.x * w8d.z + ea.y * w9d.z, 0.f);
            const float hy7 = fmaxf(a3.w + g3.w + ea.x * w8d.w + ea.y * w9d.w, 0.f);

            uint4 pkA, pkB;
            pkA.x = pad ? 0u : pack_bf2(hx0, hx1);
            pkA.y = pad ? 0u : pack_bf2(hx2, hx3);
            pkA.z = pad ? 0u : pack_bf2(hx4, hx5);
            pkA.w = pad ? 0u : pack_bf2(hx6, hx7);
            pkB.x = pad ? 0u : pack_bf2(hy0, hy1);
            pkB.y = pad ? 0u : pack_bf2(hy2, hy3);
            pkB.z = pad ? 0u : pack_bf2(hy4, hy5);
            pkB.w = pad ? 0u : pack_bf2(hy6, hy7);
            const bf16x8 afA = __builtin_bit_cast(bf16x8, pkA);
            const bf16x8 afB = __builtin_bit_cast(bf16x8, pkB);

            f32x16 c;
#pragma unroll
            for (int j = 0; j < 16; j++) c[j] = 0.0f;
            c = __builtin_amdgcn_mfma_f32_32x32x16_bf16(afA, bfA, c, 0, 0, 0);
            c = __builtin_amdgcn_mfma_f32_32x32x16_bf16(afB, bfB, c, 0, 0, 0);

            // C: col=lane&31, row=(reg&3)+8*(reg>>2)+4*hf.
            // reg groups {0-3}{4-7}{8-11}{12-15} = 4-edge groups {hf, 2+hf, 4+hf, 6+hf}.
            const float s0 = (c[0] + c[1]) + (c[2] + c[3]);
            const float s1 = (c[4] + c[5]) + (c[6] + c[7]);
            const float s2 = (c[8] + c[9]) + (c[10] + c[11]);
            const float s3 = (c[12] + c[13]) + (c[14] + c[15]);
            atomicAdd(&xpp[t0 * STR + n32], s0);   // contiguous 32/half, 2-way alias
            atomicAdd(&xpp[t1 * STR + n32], s1);
            atomicAdd(&xpp[t2 * STR + n32], s2);
            atomicAdd(&xpp[t3 * STR + n32], s3);
        }
    }
    __syncthreads();

    // ---- Stage-P constants (loaded after B to keep stage-B VGPR peak low) ----
    bf16x8 bP1a, bP1b, bP2a, bP2b;    // Wl[4:36] / Wl[40:72] B-fragments, col halves
#pragma unroll
    for (int j = 0; j < 8; j++) {
        bP1a[j] = f2bf(Wl[(4 + kh + j) * HID + m16]);
        bP1b[j] = f2bf(Wl[(4 + kh + j) * HID + 16 + m16]);
        bP2a[j] = f2bf(Wl[(40 + kh + j) * HID + m16]);
        bP2b[j] = f2bf(Wl[(40 + kh + j) * HID + 16 + m16]);
    }
    float wx1a[4], wx1b[4], wx2a[4], wx2b[4];   // x-part weights (K=4 tail)
#pragma unroll
    for (int i = 0; i < 4; i++) {
        wx1a[i] = Wl[i * HID + m16];
        wx1b[i] = Wl[i * HID + 16 + m16];
        wx2a[i] = Wl[(36 + i) * HID + m16];
        wx2b[i] = Wl[(36 + i) * HID + 16 + m16];
    }
    const float blca = bl[m16], blcb = bl[16 + m16];
    float b2k[8];
#pragma unroll
    for (int j = 0; j < 8; j++) b2k[j] = b2[kh + j];
    const int   mrow = wv * 16 + m16;                // A-row this lane owns in stage P
    const float dn   = (float)sdeg[mrow];

    // ---- Stage P: head projections via MFMA ----
    {
        const float4* xr = (const float4*)&xpp[mrow * STR + kh];
        float4 x0 = xr[0], x1 = xr[1];
        x0.x = fmaf(dn, b2k[0], x0.x); x0.y = fmaf(dn, b2k[1], x0.y);
        x0.z = fmaf(dn, b2k[2], x0.z); x0.w = fmaf(dn, b2k[3], x0.w);
        x1.x = fmaf(dn, b2k[4], x1.x); x1.y = fmaf(dn, b2k[5], x1.y);
        x1.z = fmaf(dn, b2k[6], x1.z); x1.w = fmaf(dn, b2k[7], x1.w);
        uint4 packed;
        packed.x = pack_bf2(x0.x, x0.y);
        packed.y = pack_bf2(x0.z, x0.w);
        packed.z = pack_bf2(x1.x, x1.y);
        packed.w = pack_bf2(x1.z, x1.w);
        const bf16x8 af = __builtin_bit_cast(bf16x8, packed);

        f32x4 c1a, c1b, c2a, c2b;
#pragma unroll
        for (int r = 0; r < 4; r++) {
            const float4 xv = xs4[wv * 16 + quad * 4 + r];
            float a0 = blca, a1 = blcb, a2 = 0.f, a3 = 0.f;
#pragma unroll
            for (int i = 0; i < 4; i++) {
                const float xi = (i == 0) ? xv.x : (i == 1) ? xv.y : (i == 2) ? xv.z : xv.w;
                a0 = fmaf(xi, wx1a[i], a0);
                a1 = fmaf(xi, wx1b[i], a1);
                a2 = fmaf(xi, wx2a[i], a2);
                a3 = fmaf(xi, wx2b[i], a3);
            }
            c1a[r] = a0; c1b[r] = a1; c2a[r] = a2; c2b[r] = a3;
        }
        c1a = __builtin_amdgcn_mfma_f32_16x16x32_bf16(af, bP1a, c1a, 0, 0, 0);
        c1b = __builtin_amdgcn_mfma_f32_16x16x32_bf16(af, bP1b, c1b, 0, 0, 0);
        c2a = __builtin_amdgcn_mfma_f32_16x16x32_bf16(af, bP2a, c2a, 0, 0, 0);
        c2b = __builtin_amdgcn_mfma_f32_16x16x32_bf16(af, bP2b, c2b, 0, 0, 0);

        // C layout: row = wv*16 + quad*4 + r, col = m16 / 16+m16
#pragma unroll
        for (int r = 0; r < 4; r++) {
            const int row = wv * 16 + quad * 4 + r;
            qp0[row * STR + m16]      = c1a[r];
            qp0[row * STR + 16 + m16] = c1b[r];
            qp1[row * STR + m16]      = c2a[r];
            qp1[row * STR + 16 + m16] = c2b[r];
        }
    }
    __syncthreads();

    // ---- Stage C: per-row combine + value head ----
    float vsum = 0.0f;
    {
        const float* actb = action + (size_t)b * NROWS;
        const float bvv = bv[0];
        const float* Wl72 = Wl + 72 * HID;   // loop-invariant s_loads, hoisted
#pragma unroll 1
        for (int i = 0; i < 4; i++) {
            const int na = ces[i], nb = ced[i];           // cached edge endpoints
            const float a = actb[tid + i * TPB];
            const float4* p1v = (const float4*)&qp0[na * STR];
            const float4* p2v = (const float4*)&qp1[nb * STR];
            float v0 = bvv, v1 = 0.0f;
#pragma unroll 1
            for (int q = 0; q < 8; q += 2) {
                const float4 pa0 = p1v[q],     pb0 = p2v[q];
                const float4 pa1 = p1v[q + 1], pb1 = p2v[q + 1];
                const int k = q * 4;
                v0 += fmaxf(pa0.x + pb0.x + a * Wl72[k+0], 0.f) * Wv[k+0];
                v1 += fmaxf(pa0.y + pb0.y + a * Wl72[k+1], 0.f) * Wv[k+1];
                v0 += fmaxf(pa0.z + pb0.z + a * Wl72[k+2], 0.f) * Wv[k+2];
                v1 += fmaxf(pa0.w + pb0.w + a * Wl72[k+3], 0.f) * Wv[k+3];
                v0 += fmaxf(pa1.x + pb1.x + a * Wl72[k+4], 0.f) * Wv[k+4];
                v1 += fmaxf(pa1.y + pb1.y + a * Wl72[k+5], 0.f) * Wv[k+5];
                v0 += fmaxf(pa1.z + pb1.z + a * Wl72[k+6], 0.f) * Wv[k+6];
                v1 += fmaxf(pa1.w + pb1.w + a * Wl72[k+7], 0.f) * Wv[k+7];
            }
            vsum += v0 + v1;
        }
        // factory rows 1024..1026 (na == nb)
        if (tid < NFACT) {
            const int r = NE + tid;
            const int na = NNODES - NFACT + tid;
            const float a = actb[r];
            const float4* p1v = (const float4*)&qp0[na * STR];
            const float4* p2v = (const float4*)&qp1[na * STR];
            float v = bvv;
#pragma unroll 1
            for (int q = 0; q < 8; q++) {
                const float4 pa = p1v[q], pb = p2v[q];
                const int k = q * 4;
                v += fmaxf(pa.x + pb.x + a * Wl72[k+0], 0.f) * Wv[k+0];
                v += fmaxf(pa.y + pb.y + a * Wl72[k+1], 0.f) * Wv[k+1];
                v += fmaxf(pa.z + pb.z + a * Wl72[k+2], 0.f) * Wv[k+2];
                v += fmaxf(pa.w + pb.w + a * Wl72[k+3], 0.f) * Wv[k+3];
            }
            vsum += v;
        }
    }

    // ---- block reduction ----
#pragma unroll
    for (int off = 32; off > 0; off >>= 1)
        vsum += __shfl_down(vsum, off, 64);
    if ((tid & 63) == 0) wred[tid >> 6] = vsum;
    __syncthreads();
    if (tid == 0) {
        float t = 0.0f;
#pragma unroll
        for (int w = 0; w < TPB / 64; w++) t += wred[w];
        out[b] = t;
    }
}

extern "C" void kernel_launch(void* const* d_in, const int* in_sizes, int n_in,
                              void* d_out, int out_size, void* d_ws, size_t ws_size,
                              hipStream_t stream) {
    const float* x         = (const float*)d_in[0];
    const float* edge_attr = (const float*)d_in[2];
    const float* action    = (const float*)d_in[3];
    const int*   es        = (const int*)d_in[4];
    const int*   ed        = (const int*)d_in[5];
    const float* W1        = (const float*)d_in[6];
    const float* b1        = (const float*)d_in[7];
    const float* W2        = (const float*)d_in[8];
    const float* b2        = (const float*)d_in[9];
    const float* Wl        = (const float*)d_in[10];
    const float* bl        = (const float*)d_in[11];
    const float* Wv        = (const float*)d_in[12];
    const float* bv        = (const float*)d_in[13];
    float* out = (float*)d_out;

    critic_fused<<<dim3(out_size), dim3(TPB), 0, stream>>>(
        x, edge_attr, action, es, ed, W1, b1, W2, b2, Wl, bl, Wv, bv, out);
}

// Round 14
// 125.605 us; speedup vs baseline: 1.2593x; 1.2593x over previous
//
#include <hip/hip_runtime.h>

// Problem constants
#define NNODES 64
#define HID 32
#define NFACT 3
#define NE 1024
#define NROWS (NE + NFACT)   // 1027
#define TPB 256
#define STR 36               // float row stride for xpp and P-phase qp
#define QSTRH 20             // u32 row stride for bf16 Q-phase qp (16 data + 4 pad)
#define MAXTILES 128         // 16-edge tile capacity (true max = 124)
#define EPT (NE / TPB)       // 4 edges cached per thread

typedef short bf16x8 __attribute__((ext_vector_type(8)));
typedef float f32x4  __attribute__((ext_vector_type(4)));
typedef float f32x16 __attribute__((ext_vector_type(16)));

// round-to-nearest-even two fp32 -> packed bf16x2 (lo | hi<<16)
__device__ __forceinline__ unsigned pack_bf2(float lo, float hi) {
    unsigned ul = __builtin_bit_cast(unsigned, lo);
    unsigned uh = __builtin_bit_cast(unsigned, hi);
    ul += 0x7fffu + ((ul >> 16) & 1u);
    uh += 0x7fffu + ((uh >> 16) & 1u);
    return (ul >> 16) | (uh & 0xffff0000u);
}
__device__ __forceinline__ short f2bf(float f) {
    unsigned u = __builtin_bit_cast(unsigned, f);
    u += 0x7fffu + ((u >> 16) & 1u);
    return (short)(u >> 16);
}
// unpack halves of a packed bf16x2 to fp32
__device__ __forceinline__ float bflo(unsigned u) { return __builtin_bit_cast(float, u << 16); }
__device__ __forceinline__ float bfhi(unsigned u) { return __builtin_bit_cast(float, u & 0xffff0000u); }
__device__ __forceinline__ float4 fma4(float a, float4 w, float4 c) {
    c.x = fmaf(a, w.x, c.x); c.y = fmaf(a, w.y, c.y);
    c.z = fmaf(a, w.z, c.z); c.w = fmaf(a, w.w, c.w);
    return c;
}

// R12 structure (best: 44.3us dispatch) + bf16-packed Q storage: stage B's
// 8 ds_read_b128 gathers/iter -> 4, trading DS (1 port/CU, critical) for
// VALU unpack (4 SIMDs/CU, subcritical). R13's 4-edge tiles reverted: 3x the
// atomic instructions with same-address halves serialized (44 -> 73us).
//   pep packed: low12 = edge id (0xFFF = pad), bits12-17 = dst, bits18-23 = src
__global__ __launch_bounds__(TPB, 4) void critic_fused(
    const float* __restrict__ x,
    const float* __restrict__ edge_attr,
    const float* __restrict__ action,
    const int*   __restrict__ es,
    const int*   __restrict__ ed,
    const float* __restrict__ W1,
    const float* __restrict__ b1,
    const float* __restrict__ W2,
    const float* __restrict__ b2,
    const float* __restrict__ Wl,
    const float* __restrict__ bl,
    const float* __restrict__ Wv,
    const float* __restrict__ bv,
    float* __restrict__ out)
{
    const int b    = blockIdx.x;
    const int tid  = threadIdx.x;
    const int lane = tid & 63;
    const int wv   = tid >> 6;
    const int quad = lane >> 4;
    const int m16  = lane & 15;
    const int kh   = quad * 8;

    __shared__ __align__(16) float4 xs4[NNODES];
    __shared__ __align__(16) float  xpp[NNODES * STR];
    __shared__ __align__(16) float  qp0[NNODES * STR];   // bf16 Q1 (u32 view) then fp32 P1
    __shared__ __align__(16) float  qp1[NNODES * STR];   // bf16 Q2 (u32 view) then fp32 P2
    __shared__ __align__(16) float  W1s[10 * HID];
    __shared__ float  b1s[HID];
    __shared__ float  wred[TPB / 64];
    // CSR tables (built per block, 16-edge tiles)
    __shared__ int    sdeg[NNODES], soff[NNODES], scnt[NNODES];
    __shared__ int    tns[MAXTILES];
    __shared__ int    pep[MAXTILES * 16];
    __shared__ int    snt;

    unsigned* qh0 = (unsigned*)qp0;   // bf16 Q rows: stride QSTRH u32
    unsigned* qh1 = (unsigned*)qp1;

    // ---- Stage A: stage x + W1, zero xpp, init CSR tables ----
    if (tid < NNODES) { xs4[tid] = ((const float4*)x)[b * NNODES + tid]; sdeg[tid] = 0; scnt[tid] = 0; }
    if (tid < 80) ((float4*)W1s)[tid] = ((const float4*)W1)[tid];
    if (tid < HID) b1s[tid] = b1[tid];
    if (tid < MAXTILES) tns[tid] = 0;
#pragma unroll
    for (int i = 0; i < MAXTILES * 16 / TPB; i++) pep[tid + i * TPB] = 0xFFF;  // pad, node 0
#pragma unroll 1
    for (int i = tid; i < NNODES * STR; i += TPB) xpp[i] = 0.0f;

    // cache this thread's 4 edges in registers (coalesced global reads)
    int ces[EPT], ced[EPT];
#pragma unroll
    for (int i = 0; i < EPT; i++) {
        ces[i] = es[tid + i * TPB];
        ced[i] = ed[tid + i * TPB];
    }
    __syncthreads();

    // ---- CSR count + Stage Q (independent; co-scheduled to hide latency) ----
#pragma unroll
    for (int i = 0; i < EPT; i++) atomicAdd(&sdeg[ces[i]], 1);
    {
        const int n  = lane;
        const int k0 = wv * 8;
        const float4 xv = xs4[n];
        const float4* b1v = (const float4*)&b1s[k0];
        float4 q1a = b1v[0], q1b = b1v[1];
        float4 q2a = make_float4(0.f, 0.f, 0.f, 0.f), q2b = q2a;
#pragma unroll 1
        for (int i = 0; i < 4; i++) {
            const float xi = (i == 0) ? xv.x : (i == 1) ? xv.y : (i == 2) ? xv.z : xv.w;
            const float4* wa = (const float4*)&W1s[i * HID + k0];
            const float4* wb = (const float4*)&W1s[(4 + i) * HID + k0];
            q1a = fma4(xi, wa[0], q1a); q1b = fma4(xi, wa[1], q1b);
            q2a = fma4(xi, wb[0], q2a); q2b = fma4(xi, wb[1], q2b);
        }
        uint4 p1, p2;   // pack 8 fp32 -> 4 u32 (bf16 pairs), one b128 write each
        p1.x = pack_bf2(q1a.x, q1a.y); p1.y = pack_bf2(q1a.z, q1a.w);
        p1.z = pack_bf2(q1b.x, q1b.y); p1.w = pack_bf2(q1b.z, q1b.w);
        p2.x = pack_bf2(q2a.x, q2a.y); p2.y = pack_bf2(q2a.z, q2a.w);
        p2.z = pack_bf2(q2b.x, q2b.y); p2.w = pack_bf2(q2b.z, q2b.w);
        *(uint4*)&qh0[n * QSTRH + wv * 4] = p1;
        *(uint4*)&qh1[n * QSTRH + wv * 4] = p2;
    }
    __syncthreads();

    // ---- CSR scan (wave 0) + tile-node fill ----
    if (tid < NNODES) {
        const int cnt = (sdeg[tid] + 15) >> 4;
        int scan = cnt;
#pragma unroll
        for (int o = 1; o < 64; o <<= 1) {
            const int v = __shfl_up(scan, o);
            if (tid >= o) scan += v;
        }
        const int base = scan - cnt;
        soff[tid] = base;
        if (tid == NNODES - 1) snt = scan;           // ~90-96, <=124
#pragma unroll 1
        for (int j = 0; j < cnt; j++) tns[base + j] = tid;
    }
    __syncthreads();

    // ---- CSR scatter (cached edges) ----
#pragma unroll
    for (int i = 0; i < EPT; i++) {
        const int n = ces[i];
        const int idx = atomicAdd(&scnt[n], 1);
        pep[soff[n] * 16 + idx] = (tid + i * TPB) | (ced[i] << 12) | (n << 18);
    }
    __syncthreads();

    // ---- Stage B: pair-tiled MFMA edge messages (32 edges / 2 nodes per iteration) ----
    {
        const float2* ea2 = (const float2*)edge_attr + (size_t)b * NE;
        const int NW   = TPB / 64;
        const int klo  = (lane >> 5) * 8;      // K-slice base (0 or 8)
        const int klo2 = klo >> 1;             // u32 offset of the slice
        const int n32  = lane & 31;

        const float4* w8l = (const float4*)&W1s[8 * HID + klo];
        const float4* w8h = (const float4*)&W1s[8 * HID + 16 + klo];
        const float4* w9l = (const float4*)&W1s[9 * HID + klo];
        const float4* w9h = (const float4*)&W1s[9 * HID + 16 + klo];
        const float4 w8a = w8l[0], w8b = w8l[1], w8c = w8h[0], w8d = w8h[1];
        const float4 w9a = w9l[0], w9b = w9l[1], w9c = w9h[0], w9d = w9h[1];

        bf16x8 bfA, bfB;   // W2 B-frags: B[k][n32], K-halves 0..15 / 16..31
#pragma unroll
        for (int j = 0; j < 8; j++) {
            bfA[j] = f2bf(W2[(klo + j) * HID + n32]);
            bfB[j] = f2bf(W2[(16 + klo + j) * HID + n32]);
        }

        const int np = (snt + 1) >> 1;

#pragma unroll 1
        for (int p = wv; p < np; p += NW) {
            const int raw = pep[p * 32 + n32];        // edge slot = window row n32
            const int tA  = tns[2 * p];
            const int tB  = tns[2 * p + 1];
            const int e    = raw & 0xFFF;
            const bool pad = (e == 0xFFF);
            const int d0   = (raw >> 12) & 63;
            const int nd   = (raw >> 18) & 63;        // src node of MY edge
            const float2 ea = ea2[pad ? 0 : e];

            // bf16-packed gathers: 4 x b128 total (was 8 in fp32)
            const uint4 A1 = *(const uint4*)&qh0[nd * QSTRH + klo2];
            const uint4 A2 = *(const uint4*)&qh0[nd * QSTRH + 8 + klo2];
            const uint4 G1 = *(const uint4*)&qh1[d0 * QSTRH + klo2];
            const uint4 G2 = *(const uint4*)&qh1[d0 * QSTRH + 8 + klo2];

            const float hx0 = fmaxf(bflo(A1.x) + bflo(G1.x) + ea.x * w8a.x + ea.y * w9a.x, 0.f);
            const float hx1 = fmaxf(bfhi(A1.x) + bfhi(G1.x) + ea.x * w8a.y + ea.y * w9a.y, 0.f);
            const float hx2 = fmaxf(bflo(A1.y) + bflo(G1.y) + ea.x * w8a.z + ea.y * w9a.z, 0.f);
            const float hx3 = fmaxf(bfhi(A1.y) + bfhi(G1.y) + ea.x * w8a.w + ea.y * w9a.w, 0.f);
            const float hx4 = fmaxf(bflo(A1.z) + bflo(G1.z) + ea.x * w8b.x + ea.y * w9b.x, 0.f);
            const float hx5 = fmaxf(bfhi(A1.z) + bfhi(G1.z) + ea.x * w8b.y + ea.y * w9b.y, 0.f);
            const float hx6 = fmaxf(bflo(A1.w) + bflo(G1.w) + ea.x * w8b.z + ea.y * w9b.z, 0.f);
            const float hx7 = fmaxf(bfhi(A1.w) + bfhi(G1.w) + ea.x * w8b.w + ea.y * w9b.w, 0.f);
            const float hy0 = fmaxf(bflo(A2.x) + bflo(G2.x) + ea.x * w8c.x + ea.y * w9c.x, 0.f);
            const float hy1 = fmaxf(bfhi(A2.x) + bfhi(G2.x) + ea.x * w8c.y + ea.y * w9c.y, 0.f);
            const float hy2 = fmaxf(bflo(A2.y) + bflo(G2.y) + ea.x * w8c.z + ea.y * w9c.z, 0.f);
            const float hy3 = fmaxf(bfhi(A2.y) + bfhi(G2.y) + ea.x * w8c.w + ea.y * w9c.w, 0.f);
            const float hy4 = fmaxf(bflo(A2.z) + bflo(G2.z) + ea.x * w8d.x + ea.y * w9d.x, 0.f);
            const float hy5 = fmaxf(bfhi(A2.z) + bfhi(G2.z) + ea.x * w8d.y + ea.y * w9d.y, 0.f);
            const float hy6 = fmaxf(bflo(A2.w) + bflo(G2.w) + ea.x * w8d.z + ea.y * w9d.z, 0.f);
            const float hy7 = fmaxf(bfhi(A2.w) + bfhi(G2.w) + ea.x * w8d.w + ea.y * w9d.w, 0.f);

            uint4 pkA, pkB;
            pkA.x = pad ? 0u : pack_bf2(hx0, hx1);
            pkA.y = pad ? 0u : pack_bf2(hx2, hx3);
            pkA.z = pad ? 0u : pack_bf2(hx4, hx5);
            pkA.w = pad ? 0u : pack_bf2(hx6, hx7);
            pkB.x = pad ? 0u : pack_bf2(hy0, hy1);
            pkB.y = pad ? 0u : pack_bf2(hy2, hy3);
            pkB.z = pad ? 0u : pack_bf2(hy4, hy5);
            pkB.w = pad ? 0u : pack_bf2(hy6, hy7);
            const bf16x8 afA = __builtin_bit_cast(bf16x8, pkA);
            const bf16x8 afB = __builtin_bit_cast(bf16x8, pkB);

            f32x16 c;
#pragma unroll
            for (int j = 0; j < 16; j++) c[j] = 0.0f;
            c = __builtin_amdgcn_mfma_f32_32x32x16_bf16(afA, bfA, c, 0, 0, 0);
            c = __builtin_amdgcn_mfma_f32_32x32x16_bf16(afB, bfB, c, 0, 0, 0);

            // C: col=lane&31, row=(reg&3)+8*(reg>>2)+4*(lane>>5).
            // regs 0-7 -> rows 0-15 (tile A), regs 8-15 -> rows 16-31 (tile B).
            float sA = ((c[0] + c[1]) + (c[2] + c[3])) + ((c[4] + c[5]) + (c[6] + c[7]));
            float sB = ((c[8] + c[9]) + (c[10] + c[11])) + ((c[12] + c[13]) + (c[14] + c[15]));
            sA += __shfl_xor(sA, 32);
            sB += __shfl_xor(sB, 32);
            const int   nst = (lane < 32) ? tA : tB;
            const float sv  = (lane < 32) ? sA : sB;
            atomicAdd(&xpp[nst * STR + n32], sv);     // full wave, contiguous per node
        }
    }
    __syncthreads();

    // ---- Stage-P constants (loaded after B to keep stage-B VGPR peak low) ----
    bf16x8 bP1a, bP1b, bP2a, bP2b;    // Wl[4:36] / Wl[40:72] B-fragments, col halves
#pragma unroll
    for (int j = 0; j < 8; j++) {
        bP1a[j] = f2bf(Wl[(4 + kh + j) * HID + m16]);
        bP1b[j] = f2bf(Wl[(4 + kh + j) * HID + 16 + m16]);
        bP2a[j] = f2bf(Wl[(40 + kh + j) * HID + m16]);
        bP2b[j] = f2bf(Wl[(40 + kh + j) * HID + 16 + m16]);
    }
    float wx1a[4], wx1b[4], wx2a[4], wx2b[4];   // x-part weights (K=4 tail)
#pragma unroll
    for (int i = 0; i < 4; i++) {
        wx1a[i] = Wl[i * HID + m16];
        wx1b[i] = Wl[i * HID + 16 + m16];
        wx2a[i] = Wl[(36 + i) * HID + m16];
        wx2b[i] = Wl[(36 + i) * HID + 16 + m16];
    }
    const float blca = bl[m16], blcb = bl[16 + m16];
    float b2k[8];
#pragma unroll
    for (int j = 0; j < 8; j++) b2k[j] = b2[kh + j];
    const int   mrow = wv * 16 + m16;                // A-row this lane owns in stage P
    const float dn   = (float)sdeg[mrow];

    // ---- Stage P: head projections via MFMA (fp32 outputs into stride-36 layout) ----
    {
        const float4* xr = (const float4*)&xpp[mrow * STR + kh];
        float4 x0 = xr[0], x1 = xr[1];
        x0.x = fmaf(dn, b2k[0], x0.x); x0.y = fmaf(dn, b2k[1], x0.y);
        x0.z = fmaf(dn, b2k[2], x0.z); x0.w = fmaf(dn, b2k[3], x0.w);
        x1.x = fmaf(dn, b2k[4], x1.x); x1.y = fmaf(dn, b2k[5], x1.y);
        x1.z = fmaf(dn, b2k[6], x1.z); x1.w = fmaf(dn, b2k[7], x1.w);
        uint4 packed;
        packed.x = pack_bf2(x0.x, x0.y);
        packed.y = pack_bf2(x0.z, x0.w);
        packed.z = pack_bf2(x1.x, x1.y);
        packed.w = pack_bf2(x1.z, x1.w);
        const bf16x8 af = __builtin_bit_cast(bf16x8, packed);

        f32x4 c1a, c1b, c2a, c2b;
#pragma unroll
        for (int r = 0; r < 4; r++) {
            const float4 xv = xs4[wv * 16 + quad * 4 + r];
            float a0 = blca, a1 = blcb, a2 = 0.f, a3 = 0.f;
#pragma unroll
            for (int i = 0; i < 4; i++) {
                const float xi = (i == 0) ? xv.x : (i == 1) ? xv.y : (i == 2) ? xv.z : xv.w;
                a0 = fmaf(xi, wx1a[i], a0);
                a1 = fmaf(xi, wx1b[i], a1);
                a2 = fmaf(xi, wx2a[i], a2);
                a3 = fmaf(xi, wx2b[i], a3);
            }
            c1a[r] = a0; c1b[r] = a1; c2a[r] = a2; c2b[r] = a3;
        }
        c1a = __builtin_amdgcn_mfma_f32_16x16x32_bf16(af, bP1a, c1a, 0, 0, 0);
        c1b = __builtin_amdgcn_mfma_f32_16x16x32_bf16(af, bP1b, c1b, 0, 0, 0);
        c2a = __builtin_amdgcn_mfma_f32_16x16x32_bf16(af, bP2a, c2a, 0, 0, 0);
        c2b = __builtin_amdgcn_mfma_f32_16x16x32_bf16(af, bP2b, c2b, 0, 0, 0);

        __syncthreads();   // Q-phase bf16 reads fully drained before fp32 overwrite
        // C layout: row = wv*16 + quad*4 + r, col = m16 / 16+m16
#pragma unroll
        for (int r = 0; r < 4; r++) {
            const int row = wv * 16 + quad * 4 + r;
            qp0[row * STR + m16]      = c1a[r];
            qp0[row * STR + 16 + m16] = c1b[r];
            qp1[row * STR + m16]      = c2a[r];
            qp1[row * STR + 16 + m16] = c2b[r];
        }
    }
    __syncthreads();

    // ---- Stage C: per-row combine + value head ----
    float vsum = 0.0f;
    {
        const float* actb = action + (size_t)b * NROWS;
        const float bvv = bv[0];
        const float* Wl72 = Wl + 72 * HID;   // loop-invariant s_loads, hoisted
#pragma unroll 1
        for (int i = 0; i < 4; i++) {
            const int na = ces[i], nb = ced[i];           // cached edge endpoints
            const float a = actb[tid + i * TPB];
            const float4* p1v = (const float4*)&qp0[na * STR];
            const float4* p2v = (const float4*)&qp1[nb * STR];
            float v0 = bvv, v1 = 0.0f;
#pragma unroll 1
            for (int q = 0; q < 8; q += 2) {
                const float4 pa0 = p1v[q],     pb0 = p2v[q];
                const float4 pa1 = p1v[q + 1], pb1 = p2v[q + 1];
                const int k = q * 4;
                v0 += fmaxf(pa0.x + pb0.x + a * Wl72[k+0], 0.f) * Wv[k+0];
                v1 += fmaxf(pa0.y + pb0.y + a * Wl72[k+1], 0.f) * Wv[k+1];
                v0 += fmaxf(pa0.z + pb0.z + a * Wl72[k+2], 0.f) * Wv[k+2];
                v1 += fmaxf(pa0.w + pb0.w + a * Wl72[k+3], 0.f) * Wv[k+3];
                v0 += fmaxf(pa1.x + pb1.x + a * Wl72[k+4], 0.f) * Wv[k+4];
                v1 += fmaxf(pa1.y + pb1.y + a * Wl72[k+5], 0.f) * Wv[k+5];
                v0 += fmaxf(pa1.z + pb1.z + a * Wl72[k+6], 0.f) * Wv[k+6];
                v1 += fmaxf(pa1.w + pb1.w + a * Wl72[k+7], 0.f) * Wv[k+7];
            }
            vsum += v0 + v1;
        }
        // factory rows 1024..1026 (na == nb)
        if (tid < NFACT) {
            const int r = NE + tid;
            const int na = NNODES - NFACT + tid;
            const float a = actb[r];
            const float4* p1v = (const float4*)&qp0[na * STR];
            const float4* p2v = (const float4*)&qp1[na * STR];
            float v = bvv;
#pragma unroll 1
            for (int q = 0; q < 8; q++) {
                const float4 pa = p1v[q], pb = p2v[q];
                const int k = q * 4;
                v += fmaxf(pa.x + pb.x + a * Wl72[k+0], 0.f) * Wv[k+0];
                v += fmaxf(pa.y + pb.y + a * Wl72[k+1], 0.f) * Wv[k+1];
                v += fmaxf(pa.z + pb.z + a * Wl72[k+2], 0.f) * Wv[k+2];
                v += fmaxf(pa.w + pb.w + a * Wl72[k+3], 0.f) * Wv[k+3];
            }
            vsum += v;
        }
    }

    // ---- block reduction ----
#pragma unroll
    for (int off = 32; off > 0; off >>= 1)
        vsum += __shfl_down(vsum, off, 64);
    if ((tid & 63) == 0) wred[tid >> 6] = vsum;
    __syncthreads();
    if (tid == 0) {
        float t = 0.0f;
#pragma unroll
        for (int w = 0; w < TPB / 64; w++) t += wred[w];
        out[b] = t;
    }
}

extern "C" void kernel_launch(void* const* d_in, const int* in_sizes, int n_in,
                              void* d_out, int out_size, void* d_ws, size_t ws_size,
                              hipStream_t stream) {
    const float* x         = (const float*)d_in[0];
    const float* edge_attr = (const float*)d_in[2];
    const float* action    = (const float*)d_in[3];
    const int*   es        = (const int*)d_in[4];
    const int*   ed        = (const int*)d_in[5];
    const float* W1        = (const float*)d_in[6];
    const float* b1        = (const float*)d_in[7];
    const float* W2        = (const float*)d_in[8];
    const float* b2        = (const float*)d_in[9];
    const float* Wl        = (const float*)d_in[10];
    const float* bl        = (const float*)d_in[11];
    const float* Wv        = (const float*)d_in[12];
    const float* bv        = (const float*)d_in[13];
    float* out = (float*)d_out;

    critic_fused<<<dim3(out_size), dim3(TPB), 0, stream>>>(
        x, edge_attr, action, es, ed, W1, b1, W2, b2, Wl, bl, Wv, bv, out);
}